// Round 1
// baseline (885.137 us; speedup 1.0000x reference)
//
#include <hip/hip_runtime.h>

#define CIN 32
#define COUT 64
#define OD0 100
#define OD1 100
#define OD2 8

// ---------- rank selection: two-level 16-bit radix histograms ----------

__global__ void hist_hi_kernel(const float* __restrict__ mask, int n, int* __restrict__ hist) {
    int i = blockIdx.x * blockDim.x + threadIdx.x;
    if (i >= n) return;
    unsigned bits = __float_as_uint(mask[i]);   // mask in [0,1): uint order == float order
    atomicAdd(&hist[bits >> 16], 1);
}

__global__ void hist_lo_kernel(const float* __restrict__ mask, int n,
                               const int* __restrict__ sel, int* __restrict__ hist) {
    int i = blockIdx.x * blockDim.x + threadIdx.x;
    if (i >= n) return;
    unsigned bits = __float_as_uint(mask[i]);
    if ((int)(bits >> 16) == sel[0]) atomicAdd(&hist[bits & 0xFFFFu], 1);
}

// One block, 256 threads. Finds bucket containing `rank` and residual rank.
__global__ void select_kernel(const int* __restrict__ hist, const int* rankSrc,
                              int rankConst, int* outPair) {
    __shared__ int partial[256];
    __shared__ int scan[257];
    int t = threadIdx.x;
    int rank = rankSrc ? *rankSrc : rankConst;
    const int* h = hist + t * 256;
    int sum = 0;
    for (int j = 0; j < 256; j++) sum += h[j];
    partial[t] = sum;
    __syncthreads();
    if (t == 0) {
        int c = 0;
        for (int j = 0; j < 256; j++) { scan[j] = c; c += partial[j]; }
        scan[256] = c;
    }
    __syncthreads();
    int base = scan[t];
    if (rank >= base && rank < scan[t + 1]) {
        int c = base;
        for (int j = 0; j < 256; j++) {
            int hv = h[j];
            if (rank < c + hv) { outPair[0] = t * 256 + j; outPair[1] = rank - c; break; }
            c += hv;
        }
    }
}

// ---------- main scatter conv: one wave per point, lane = output channel ----------

__global__ void __launch_bounds__(256)
scatter_kernel(const float* __restrict__ feat, const int* __restrict__ coors,
               const float* __restrict__ mask, const float* __restrict__ W,
               const int* __restrict__ sel, float* __restrict__ out,
               int* __restrict__ keep, int n) {
    int gid = blockIdx.x * blockDim.x + threadIdx.x;
    int wave = gid >> 6;
    int lane = threadIdx.x & 63;
    if (wave >= n) return;

    const int4 c4 = ((const int4*)coors)[wave];
    int bb = c4.x, pz = c4.y, py = c4.z, px = c4.w;

    unsigned thrBits = ((unsigned)sel[0] << 16) | (unsigned)sel[2];
    float thr = __uint_as_float(thrBits);
    bool imp = mask[wave] >= thr;

    // stride-2 + pad-1: per dim at most 2 valid taps (parity of pos+1)
    int oz[2], ozo[2], nz = 0;
    int oy[2], oyo[2], ny = 0;
    int ox[2], oxo[2], nx = 0;
#pragma unroll
    for (int o = 0; o < 3; o++) {
        int num = pz + 1 - o;
        if (num >= 0 && !(num & 1) && (num >> 1) < OD0) { oz[nz] = num >> 1; ozo[nz] = o; nz++; }
        num = py + 1 - o;
        if (num >= 0 && !(num & 1) && (num >> 1) < OD1) { oy[ny] = num >> 1; oyo[ny] = o; ny++; }
        num = px + 1 - o;
        if (num >= 0 && !(num & 1) && (num >> 1) < OD2) { ox[nx] = num >> 1; oxo[nx] = o; nx++; }
    }

    // all lanes broadcast-load this point's 32 features (128 B, L1-served)
    float f[CIN];
    const float4* fp = (const float4*)(feat + (size_t)wave * CIN);
#pragma unroll
    for (int j = 0; j < CIN / 4; j++) {
        float4 v = fp[j];
        f[4 * j + 0] = v.x; f[4 * j + 1] = v.y; f[4 * j + 2] = v.z; f[4 * j + 3] = v.w;
    }

    for (int a = 0; a < nz; a++)
        for (int b = 0; b < ny; b++)
            for (int c = 0; c < nx; c++) {
                int woff = ((ozo[a] * 3 + oyo[b]) * 3 + oxo[c]) * (CIN * COUT);
                const float* w = W + woff + lane;     // lane c: column c, coalesced rows
                float acc = 0.f;
#pragma unroll
                for (int k = 0; k < CIN; k++) acc = fmaf(f[k], w[k * COUT], acc);
                int lin = ((bb * OD0 + oz[a]) * OD1 + oy[b]) * OD2 + ox[c];
                atomicAdd(out + (size_t)lin * COUT + lane, acc);
                if (imp && lane == 0) keep[lin] = 1;  // same-value race: benign
            }
}

// ---------- zero pruned cells ----------

__global__ void finalize_kernel(float* __restrict__ out, const int* __restrict__ keep, int numOut) {
    int t = blockIdx.x * blockDim.x + threadIdx.x;
    if (t >= numOut * (COUT / 4)) return;
    int o = t >> 4;   // 16 float4 per output cell
    if (!keep[o]) ((float4*)out)[t] = make_float4(0.f, 0.f, 0.f, 0.f);
}

extern "C" void kernel_launch(void* const* d_in, const int* in_sizes, int n_in,
                              void* d_out, int out_size, void* d_ws, size_t ws_size,
                              hipStream_t stream) {
    const float* feat  = (const float*)d_in[0];   // (N, 32) f32
    const int*   coors = (const int*)d_in[1];     // (N, 4)  i32
    const float* mask  = (const float*)d_in[2];   // (N,)    f32
    const float* W     = (const float*)d_in[3];   // (3,3,3,32,64) f32

    int n = in_sizes[2];                 // N (mask element count)
    int numOut = out_size / COUT;        // 160000
    int rank = (int)(n * 0.5);           // int(N * PRUNING_RATIO)

    char* ws = (char*)d_ws;
    int* histHi = (int*)ws;                              // 65536 ints
    int* histLo = (int*)(ws + 65536 * 4);                // 65536 ints
    int* sel    = (int*)(ws + 2 * 65536 * 4);            // [hiBucket, rank2, loBucket, pad]
    int* keep   = (int*)(ws + 2 * 65536 * 4 + 64);       // numOut ints
    size_t zeroBytes = 2 * 65536 * 4 + 64 + (size_t)numOut * 4;

    hipMemsetAsync(d_out, 0, (size_t)out_size * sizeof(float), stream);
    hipMemsetAsync(d_ws, 0, zeroBytes, stream);

    const int blk = 256;
    int gN = (n + blk - 1) / blk;
    hist_hi_kernel<<<gN, blk, 0, stream>>>(mask, n, histHi);
    select_kernel<<<1, 256, 0, stream>>>(histHi, nullptr, rank, sel);
    hist_lo_kernel<<<gN, blk, 0, stream>>>(mask, n, sel, histLo);
    select_kernel<<<1, 256, 0, stream>>>(histLo, sel + 1, 0, sel + 2);

    long long threads = (long long)n * 64;
    int gScatter = (int)((threads + blk - 1) / blk);
    scatter_kernel<<<gScatter, blk, 0, stream>>>(feat, coors, mask, W, sel,
                                                 (float*)d_out, keep, n);

    int fin = numOut * (COUT / 4);
    finalize_kernel<<<(fin + blk - 1) / blk, blk, 0, stream>>>((float*)d_out, keep, numOut);
}